// Round 7
// baseline (79.894 us; speedup 1.0000x reference)
//
#include <hip/hip_runtime.h>
#include <hip/hip_bf16.h>
#include <hip/hip_cooperative_groups.h>

namespace cg = cooperative_groups;

#define NN 6400   // total nodes
#define NG 200    // nodes per graph
#define NB 32     // graphs
#define FF 128    // F_in == F_out

typedef __attribute__((ext_vector_type(8))) short s8v;  // 8 x bf16 (4 VGPRs)
typedef __attribute__((ext_vector_type(4))) float f4v;  // MFMA accumulator

__device__ __forceinline__ short f2bf(float x) {
  unsigned u = __float_as_uint(x);
  u += 0x7FFFu + ((u >> 16) & 1u);   // RNE
  return (short)(u >> 16);
}
__device__ __forceinline__ float sigm(float x) {
  return __builtin_amdgcn_rcpf(1.f + __expf(-x));
}
// Bank-swizzle for LDS fragment granules (bijective per 64-granule tile).
__device__ __forceinline__ int swz(int g) {
  return g ^ ((g >> 4) & 3) ^ ((g >> 6) & 7);
}

// supp fragment layout: [b][kc=7][nt=8][lane=64][e=8] bf16 (K padded to 224)
__device__ __forceinline__ size_t supp_elem(int b, int kloc, int n) {
  return ((((size_t)b * 7 + (kloc >> 5)) * 8 + (n >> 4)) * 64
          + (n & 15) + ((kloc >> 3) & 3) * 16) * 8 + (kloc & 7);
}

// ---------------------------------------------------------------------------
// Cooperative fused kernel, 488 blocks (all co-resident: 32KB LDS, <=128 VGPR
// -> >=2 blocks/CU -> 512 slots >= 488):
//   0..199  : PRODUCER — msk row + support = feat @ W (MFMA) -> bf16 B-frags
//   200..231: PAD      — zero-fill K-pad supp fragment slots
//   232..487: CONSUMER — prefetch adj to VGPRs (overlaps producers),
//             grid.sync(), build M A-frags in LDS, MFMA vs supp, store out.
// ---------------------------------------------------------------------------
__global__ __launch_bounds__(256, 2) void fused_coop(
    const float* __restrict__ feat, const float* __restrict__ weight,
    const float* __restrict__ rew, const float* __restrict__ adj,
    short* __restrict__ supp, float* __restrict__ msk,
    float* __restrict__ out)
{
  __shared__ char lds_raw[32768];
  const int t = threadIdx.x;
  const int bid = blockIdx.x;
  cg::grid_group grid = cg::this_grid();

  if (bid < 200) {                       // ================ PRODUCER ================
    s8v* sW = (s8v*)lds_raw;             // W B-frags [kc=4][nt=8][lane=64]

    // msk row r = bid: 0.5(R+R^T)+I, zero-padded to 224 cols
    {
      const int r = bid;
      if (t < 224) {
        float v = 0.f;
        if (t < 200)
          v = 0.5f * (rew[r * NG + t] + rew[t * NG + r]) + (r == t ? 1.f : 0.f);
        msk[r * 224 + t] = v;
      }
    }

    // stage W fragments (coalesced dword loads across lanes per e)
    for (int p = 0; p < 8; ++p) {
      const int idx = t + p * 256;
      const int n = idx & 127, kg = idx >> 7;
      s8v v;
#pragma unroll
      for (int e = 0; e < 8; ++e)
        v[e] = f2bf(weight[(kg * 8 + e) * FF + n]);
      sW[((kg >> 2) * 8 + (n >> 4)) * 64 + (n & 15) + (kg & 3) * 16] = v;
    }
    __syncthreads();

    const int w = t >> 6, l = t & 63;
    const int mt = w >> 1, nh = w & 1;
    const int arow = bid * 32 + mt * 16 + (l & 15);
    const int klane = (l >> 4) * 8;

    f4v acc0 = {0.f,0.f,0.f,0.f}, acc1 = acc0, acc2 = acc0, acc3 = acc0;
#pragma unroll
    for (int kc = 0; kc < 4; ++kc) {
      const float* fp = feat + (size_t)arow * FF + kc * 32 + klane;
      const float4 fa = *(const float4*)fp;
      const float4 fb = *(const float4*)(fp + 4);
      s8v af;
      af[0]=f2bf(fa.x); af[1]=f2bf(fa.y); af[2]=f2bf(fa.z); af[3]=f2bf(fa.w);
      af[4]=f2bf(fb.x); af[5]=f2bf(fb.y); af[6]=f2bf(fb.z); af[7]=f2bf(fb.w);
      acc0 = __builtin_amdgcn_mfma_f32_16x16x32_bf16(af, sW[(kc*8 + nh*4 + 0)*64 + l], acc0, 0,0,0);
      acc1 = __builtin_amdgcn_mfma_f32_16x16x32_bf16(af, sW[(kc*8 + nh*4 + 1)*64 + l], acc1, 0,0,0);
      acc2 = __builtin_amdgcn_mfma_f32_16x16x32_bf16(af, sW[(kc*8 + nh*4 + 2)*64 + l], acc2, 0,0,0);
      acc3 = __builtin_amdgcn_mfma_f32_16x16x32_bf16(af, sW[(kc*8 + nh*4 + 3)*64 + l], acc3, 0,0,0);
    }

    // scatter-store acc as bf16 B-fragments (D: col=l&15, row=(l>>4)*4+reg)
#pragma unroll
    for (int reg = 0; reg < 4; ++reg) {
      const int rr = bid * 32 + mt * 16 + (l >> 4) * 4 + reg;
      const unsigned bb = (unsigned)rr / 200u;
      const int kloc = rr - (int)bb * 200;
      const int n0 = nh * 64 + (l & 15);
      supp[supp_elem(bb, kloc, n0)]      = f2bf(acc0[reg]);
      supp[supp_elem(bb, kloc, n0 + 16)] = f2bf(acc1[reg]);
      supp[supp_elem(bb, kloc, n0 + 32)] = f2bf(acc2[reg]);
      supp[supp_elem(bb, kloc, n0 + 48)] = f2bf(acc3[reg]);
    }

    grid.sync();
    return;
  }

  if (bid < 232) {                       // ================ PAD-ZERO ================
    const int b = bid - 200;
    const size_t base = (((size_t)b * 7 + 6) * 8) * 512;  // [b][kc=6][0][0][0]
    for (int q = t; q < 1536; q += 256) {
      const int nt = q / 192, p = q - nt * 192;
      unsigned* dst = (unsigned*)(supp + base + (size_t)nt * 512 + 128) + p;
      *dst = 0u;
    }
    grid.sync();
    return;
  }

  // ================ CONSUMER ================
  const int m = bid - 232;
  const int sw2 = (m & 7) * 32 + (m >> 3);  // colocate a graph's 8 slabs per XCD
  const int b = sw2 >> 3, slab = sw2 & 7;
  const int i0 = slab * 25;

  // Prefetch adj into VGPRs (independent of producers; overlaps their work).
  float4 pa0[4], pa1[4];
  bool okf[4];
#pragma unroll
  for (int p = 0; p < 4; ++p) {
    const int idx = t + p * 256;
    const int i = idx / 28, jg = idx - i * 28;
    const int gi = i0 + i;
    okf[p] = (idx < 896) & (jg < 25) & (gi < 200);
    if (okf[p]) {
      const float* ap = adj + ((size_t)(b * NG + gi) * NN + b * NG + jg * 8);
      pa0[p] = *(const float4*)ap;
      pa1[p] = *(const float4*)(ap + 4);
    } else {
      pa0[p] = make_float4(0.f, 0.f, 0.f, 0.f);
      pa1[p] = make_float4(0.f, 0.f, 0.f, 0.f);
    }
  }

  grid.sync();                           // supp + msk now visible

  // Phase A: M = sigmoid(adj) * msk -> A-fragments in LDS (swizzled).
  s8v* sM = (s8v*)lds_raw;               // [mt=2][kc=7][lane=64], 14 KB
#pragma unroll
  for (int p = 0; p < 4; ++p) {
    const int idx = t + p * 256;
    if (idx < 896) {
      const int i = idx / 28, jg = idx - i * 28;
      const int gi = i0 + i;
      s8v v = {0,0,0,0,0,0,0,0};
      if (okf[p]) {
        const float* mp = msk + gi * 224 + jg * 8;
        const float4 m0 = *(const float4*)mp;
        const float4 m1 = *(const float4*)(mp + 4);
        v[0] = f2bf(m0.x * sigm(pa0[p].x));
        v[1] = f2bf(m0.y * sigm(pa0[p].y));
        v[2] = f2bf(m0.z * sigm(pa0[p].z));
        v[3] = f2bf(m0.w * sigm(pa0[p].w));
        v[4] = f2bf(m1.x * sigm(pa1[p].x));
        v[5] = f2bf(m1.y * sigm(pa1[p].y));
        v[6] = f2bf(m1.z * sigm(pa1[p].z));
        v[7] = f2bf(m1.w * sigm(pa1[p].w));
      }
      const int g = ((i >> 4) * 7 + (jg >> 2)) * 64 + (i & 15) + (jg & 3) * 16;
      sM[swz(g)] = v;
    }
  }
  __syncthreads();

  // Phase B: 7 K-chunks x 4 N-tiles of MFMA against supp B-frags (L2-resident).
  const int w = t >> 6, l = t & 63;
  const int mt = w >> 1, nh = w & 1;
  const s8v* sb = (const s8v*)supp + (size_t)b * 7 * 8 * 64 + (nh * 4) * 64 + l;

  f4v acc0 = {0.f,0.f,0.f,0.f}, acc1 = acc0, acc2 = acc0, acc3 = acc0;
#pragma unroll
  for (int kc = 0; kc < 7; ++kc) {
    const s8v af = sM[swz((mt * 7 + kc) * 64 + l)];
    acc0 = __builtin_amdgcn_mfma_f32_16x16x32_bf16(af, sb[(kc*8 + 0)*64], acc0, 0,0,0);
    acc1 = __builtin_amdgcn_mfma_f32_16x16x32_bf16(af, sb[(kc*8 + 1)*64], acc1, 0,0,0);
    acc2 = __builtin_amdgcn_mfma_f32_16x16x32_bf16(af, sb[(kc*8 + 2)*64], acc2, 0,0,0);
    acc3 = __builtin_amdgcn_mfma_f32_16x16x32_bf16(af, sb[(kc*8 + 3)*64], acc3, 0,0,0);
  }

  // store (guard: only first 25 computed rows are real)
#pragma unroll
  for (int reg = 0; reg < 4; ++reg) {
    const int rl = mt * 16 + (l >> 4) * 4 + reg;
    if (rl < 25) {
      const size_t o = (size_t)(b * NG + i0 + rl) * FF + nh * 64 + (l & 15);
      out[o]      = acc0[reg];
      out[o + 16] = acc1[reg];
      out[o + 32] = acc2[reg];
      out[o + 48] = acc3[reg];
    }
  }
}

// ---------------------------------------------------------------------------
extern "C" void kernel_launch(void* const* d_in, const int* in_sizes, int n_in,
                              void* d_out, int out_size, void* d_ws, size_t ws_size,
                              hipStream_t stream)
{
  const float* adj    = (const float*)d_in[0];  // [6400, 6400]
  const float* feat   = (const float*)d_in[1];  // [6400, 128]
  const float* weight = (const float*)d_in[2];  // [128, 128]
  const float* rew    = (const float*)d_in[3];  // [200, 200]
  float*       out    = (float*)d_out;          // [6400, 128]

  short* supp = (short*)d_ws;                        // 1,835,008 B
  float* msk  = (float*)((char*)d_ws + 1835008);     //   179,200 B

  void* args[] = {(void*)&feat, (void*)&weight, (void*)&rew, (void*)&adj,
                  (void*)&supp, (void*)&msk, (void*)&out};
  hipLaunchCooperativeKernel((const void*)fused_coop, dim3(488), dim3(256),
                             args, 0, stream);
}

// Round 8
// 18.247 us; speedup vs baseline: 4.3784x; 4.3784x over previous
//
#include <hip/hip_runtime.h>
#include <hip/hip_bf16.h>

#define NN 6400   // total nodes
#define NG 200    // nodes per graph
#define NB 32     // graphs
#define FF 128    // F_in == F_out

typedef __attribute__((ext_vector_type(8))) short s8v;  // 8 x bf16 (4 VGPRs)
typedef __attribute__((ext_vector_type(4))) float f4v;  // MFMA accumulator

__device__ __forceinline__ short f2bf(float x) {
  unsigned u = __float_as_uint(x);
  u += 0x7FFFu + ((u >> 16) & 1u);   // RNE
  return (short)(u >> 16);
}
__device__ __forceinline__ float sigm(float x) {
  return __builtin_amdgcn_rcpf(1.f + __expf(-x));
}

// supp fragment layout: [b][kc=7][nt=8][lane=64][e=8] bf16 (K padded to 224)
__device__ __forceinline__ size_t supp_elem(int b, int kloc, int n) {
  return ((((size_t)b * 7 + (kloc >> 5)) * 8 + (n >> 4)) * 64
          + (n & 15) + ((kloc >> 3) & 3) * 16) * 8 + (kloc & 7);
}

// M fragment layout: [b*8+slab][mt=2][kc=7][lane=64][e=8] bf16
#define SUPP_SHORTS  (32 * 7 * 8 * 512)          // 917,504 shorts
#define MF_PER_SLAB  (2 * 7 * 64 * 8)            // 7,168 shorts
#define RT_STRIDE    204

// ---------------------------------------------------------------------------
// K1, 488 fully-independent blocks (no cross-block dependency, no sync):
//   0..199  : support = feat @ W (MFMA) -> bf16 B-frags in ws
//   200..231: zero-fill K-pad (k=200..223) supp fragment slots
//   232..487: M = sigmoid(adj_bb)*(0.5(R+R^T)+I) -> bf16 A-frags in ws
//             (adj prefetched to VGPRs first; rew^T staged via ALIGNED
//              full-row float4 window — the round-4 coalescing bug fixed)
// ---------------------------------------------------------------------------
__global__ __launch_bounds__(256) void prep_kernel(
    const float* __restrict__ feat, const float* __restrict__ weight,
    const float* __restrict__ rew, const float* __restrict__ adj,
    short* __restrict__ supp, short* __restrict__ mfrag)
{
  __shared__ char lds_raw[32768];
  const int t = threadIdx.x;
  const int bid = blockIdx.x;

  if (bid < 200) {                       // ======== support build ========
    s8v* sW = (s8v*)lds_raw;             // W B-frags [kc=4][nt=8][lane=64]

    for (int p = 0; p < 8; ++p) {
      const int idx = t + p * 256;
      const int n = idx & 127, kg = idx >> 7;
      s8v v;
#pragma unroll
      for (int e = 0; e < 8; ++e)
        v[e] = f2bf(weight[(kg * 8 + e) * FF + n]);
      sW[((kg >> 2) * 8 + (n >> 4)) * 64 + (n & 15) + (kg & 3) * 16] = v;
    }
    __syncthreads();

    const int w = t >> 6, l = t & 63;
    const int mt = w >> 1, nh = w & 1;
    const int arow = bid * 32 + mt * 16 + (l & 15);
    const int klane = (l >> 4) * 8;

    f4v acc0 = {0.f,0.f,0.f,0.f}, acc1 = acc0, acc2 = acc0, acc3 = acc0;
#pragma unroll
    for (int kc = 0; kc < 4; ++kc) {
      const float* fp = feat + (size_t)arow * FF + kc * 32 + klane;
      const float4 fa = *(const float4*)fp;
      const float4 fb = *(const float4*)(fp + 4);
      s8v af;
      af[0]=f2bf(fa.x); af[1]=f2bf(fa.y); af[2]=f2bf(fa.z); af[3]=f2bf(fa.w);
      af[4]=f2bf(fb.x); af[5]=f2bf(fb.y); af[6]=f2bf(fb.z); af[7]=f2bf(fb.w);
      acc0 = __builtin_amdgcn_mfma_f32_16x16x32_bf16(af, sW[(kc*8 + nh*4 + 0)*64 + l], acc0, 0,0,0);
      acc1 = __builtin_amdgcn_mfma_f32_16x16x32_bf16(af, sW[(kc*8 + nh*4 + 1)*64 + l], acc1, 0,0,0);
      acc2 = __builtin_amdgcn_mfma_f32_16x16x32_bf16(af, sW[(kc*8 + nh*4 + 2)*64 + l], acc2, 0,0,0);
      acc3 = __builtin_amdgcn_mfma_f32_16x16x32_bf16(af, sW[(kc*8 + nh*4 + 3)*64 + l], acc3, 0,0,0);
    }

#pragma unroll
    for (int reg = 0; reg < 4; ++reg) {
      const int rr = bid * 32 + mt * 16 + (l >> 4) * 4 + reg;
      const unsigned bb = (unsigned)rr / 200u;
      const int kloc = rr - (int)bb * 200;
      const int n0 = nh * 64 + (l & 15);
      supp[supp_elem(bb, kloc, n0)]      = f2bf(acc0[reg]);
      supp[supp_elem(bb, kloc, n0 + 16)] = f2bf(acc1[reg]);
      supp[supp_elem(bb, kloc, n0 + 32)] = f2bf(acc2[reg]);
      supp[supp_elem(bb, kloc, n0 + 48)] = f2bf(acc3[reg]);
    }
    return;
  }

  if (bid < 232) {                       // ======== K-pad zero-fill ========
    const int b = bid - 200;
    const size_t base = (((size_t)b * 7 + 6) * 8) * 512;  // [b][kc=6][0][0][0]
    for (int q = t; q < 1536; q += 256) {
      const int nt = q / 192, p = q - nt * 192;
      unsigned* dst = (unsigned*)(supp + base + (size_t)nt * 512 + 128) + p;
      *dst = 0u;
    }
    return;
  }

  // ======== M-fragment build ========
  const int m = bid - 232;
  const int b = m >> 3, slab = m & 7;    // writer XCD = bid%8 = slab
  const int i0 = slab * 25;
  float* sRT = (float*)lds_raw;          // [25][204] f32 rew^T slice (20.4 KB)

  // prefetch adj into VGPRs (HBM latency hides under rew staging below)
  float4 pa0[4], pa1[4];
  bool okf[4];
#pragma unroll
  for (int p = 0; p < 4; ++p) {
    const int idx = t + p * 256;
    const int i = idx / 28, jg = idx - i * 28;
    const int gi = i0 + i;
    okf[p] = (idx < 896) & (jg < 25) & (gi < 200);
    if (okf[p]) {
      const float* ap = adj + ((size_t)(b * NG + gi) * NN + b * NG + jg * 8);
      pa0[p] = *(const float4*)ap;
      pa1[p] = *(const float4*)(ap + 4);
    } else {
      pa0[p] = make_float4(0.f,0.f,0.f,0.f);
      pa1[p] = make_float4(0.f,0.f,0.f,0.f);
    }
  }

  // stage rew^T slice via ALIGNED full-row float4 reads (cols i0..i0+24)
  {
    const int col0 = (i0 > NG - 28) ? ((NG - 28) & ~3) : (i0 & ~3);
    for (int p = 0; p < 6; ++p) {
      const int idx = t + p * 256;              // 200 rows x 7 float4
      if (idx < 1400) {
        const int j = idx / 7, f4 = idx - j * 7;
        const float4 v = *(const float4*)&rew[j * NG + col0 + f4 * 4];
#pragma unroll
        for (int e = 0; e < 4; ++e) {
          const int c = col0 + f4 * 4 + e - i0;
          if (0 <= c && c < 25) sRT[c * RT_STRIDE + j] = ((const float*)&v)[e];
        }
      }
    }
  }
  __syncthreads();

  short* mf = mfrag + (size_t)m * MF_PER_SLAB;
#pragma unroll
  for (int p = 0; p < 4; ++p) {
    const int idx = t + p * 256;
    if (idx < 896) {                     // 32 rows x 28 j-groups
      const int i = idx / 28, jg = idx - i * 28;
      const int gi = i0 + i;
      s8v v = {0,0,0,0,0,0,0,0};
      if (okf[p]) {
        const float* rp = rew + gi * NG + jg * 8;
        const float4 r0 = *(const float4*)rp;
        const float4 r1 = *(const float4*)(rp + 4);
        const float4 t0 = *(const float4*)&sRT[i * RT_STRIDE + jg * 8];
        const float4 t1 = *(const float4*)&sRT[i * RT_STRIDE + jg * 8 + 4];
        const int jd = gi - jg * 8;      // diagonal when jd == e
        v[0] = f2bf((0.5f*(r0.x + t0.x) + (jd==0)) * sigm(pa0[p].x));
        v[1] = f2bf((0.5f*(r0.y + t0.y) + (jd==1)) * sigm(pa0[p].y));
        v[2] = f2bf((0.5f*(r0.z + t0.z) + (jd==2)) * sigm(pa0[p].z));
        v[3] = f2bf((0.5f*(r0.w + t0.w) + (jd==3)) * sigm(pa0[p].w));
        v[4] = f2bf((0.5f*(r1.x + t1.x) + (jd==4)) * sigm(pa1[p].x));
        v[5] = f2bf((0.5f*(r1.y + t1.y) + (jd==5)) * sigm(pa1[p].y));
        v[6] = f2bf((0.5f*(r1.z + t1.z) + (jd==6)) * sigm(pa1[p].z));
        v[7] = f2bf((0.5f*(r1.w + t1.w) + (jd==7)) * sigm(pa1[p].w));
      }
      const int gran = ((i >> 4) * 7 + (jg >> 2)) * 64 + (i & 15) + (jg & 3) * 16;
      *(s8v*)(mf + (size_t)gran * 8) = v;
    }
  }
}

// ---------------------------------------------------------------------------
// K2, 256 blocks: pure MFMA. out_b slab = M_frags @ supp_frags.
// bid -> (b = bid>>3, slab = bid&7) so bid%8 == slab == XCD of the K1 writer.
// ---------------------------------------------------------------------------
__global__ __launch_bounds__(256) void gemm_kernel(
    const short* __restrict__ mfrag, const short* __restrict__ supp,
    float* __restrict__ out)
{
  const int t = threadIdx.x;
  const int bid = blockIdx.x;
  const int b = bid >> 3, slab = bid & 7;
  const int i0 = slab * 25;

  const int w = t >> 6, l = t & 63;
  const int mt = w >> 1, nh = w & 1;

  const s8v* am = (const s8v*)(mfrag + (size_t)bid * MF_PER_SLAB) + (mt * 7) * 64 + l;
  const s8v* sb = (const s8v*)supp + (size_t)b * 7 * 8 * 64 + (nh * 4) * 64 + l;

  f4v acc0 = {0.f,0.f,0.f,0.f}, acc1 = acc0, acc2 = acc0, acc3 = acc0;
#pragma unroll
  for (int kc = 0; kc < 7; ++kc) {
    const s8v af = am[kc * 64];
    acc0 = __builtin_amdgcn_mfma_f32_16x16x32_bf16(af, sb[(kc*8 + 0)*64], acc0, 0,0,0);
    acc1 = __builtin_amdgcn_mfma_f32_16x16x32_bf16(af, sb[(kc*8 + 1)*64], acc1, 0,0,0);
    acc2 = __builtin_amdgcn_mfma_f32_16x16x32_bf16(af, sb[(kc*8 + 2)*64], acc2, 0,0,0);
    acc3 = __builtin_amdgcn_mfma_f32_16x16x32_bf16(af, sb[(kc*8 + 3)*64], acc3, 0,0,0);
  }

#pragma unroll
  for (int reg = 0; reg < 4; ++reg) {
    const int rl = mt * 16 + (l >> 4) * 4 + reg;
    if (rl < 25) {
      const size_t o = (size_t)(b * NG + i0 + rl) * FF + nh * 64 + (l & 15);
      out[o]      = acc0[reg];
      out[o + 16] = acc1[reg];
      out[o + 32] = acc2[reg];
      out[o + 48] = acc3[reg];
    }
  }
}

// ---------------------------------------------------------------------------
extern "C" void kernel_launch(void* const* d_in, const int* in_sizes, int n_in,
                              void* d_out, int out_size, void* d_ws, size_t ws_size,
                              hipStream_t stream)
{
  const float* adj    = (const float*)d_in[0];  // [6400, 6400]
  const float* feat   = (const float*)d_in[1];  // [6400, 128]
  const float* weight = (const float*)d_in[2];  // [128, 128]
  const float* rew    = (const float*)d_in[3];  // [200, 200]
  float*       out    = (float*)d_out;          // [6400, 128]

  short* supp  = (short*)d_ws;                  // 1,835,008 B
  short* mfrag = supp + SUPP_SHORTS;            // 3,670,016 B

  prep_kernel<<<488, 256, 0, stream>>>(feat, weight, rew, adj, supp, mfrag);
  gemm_kernel<<<256, 256, 0, stream>>>(mfrag, supp, out);
}

// Round 9
// 14.668 us; speedup vs baseline: 5.4467x; 1.2440x over previous
//
#include <hip/hip_runtime.h>
#include <hip/hip_bf16.h>

#define NN 6400   // total nodes
#define NG 200    // nodes per graph
#define NB 32     // graphs
#define FF 128    // F_in == F_out

typedef __attribute__((ext_vector_type(8))) short s8v;  // 8 x bf16 (4 VGPRs)
typedef __attribute__((ext_vector_type(4))) float f4v;  // MFMA accumulator

__device__ __forceinline__ short f2bf(float x) {
  unsigned u = __float_as_uint(x);
  u += 0x7FFFu + ((u >> 16) & 1u);   // RNE
  return (short)(u >> 16);
}
__device__ __forceinline__ float sigm(float x) {
  return __builtin_amdgcn_rcpf(1.f + __expf(-x));
}
// Bank-swizzle for LDS fragment granules (bijective per 64-granule tile).
__device__ __forceinline__ int swz(int g) {
  return g ^ ((g >> 4) & 3) ^ ((g >> 6) & 7);
}

// supp fragment layout: [b][kc=7][nt=8][lane=64][e=8] bf16 (K padded to 224)
__device__ __forceinline__ size_t supp_elem(int b, int kloc, int n) {
  return ((((size_t)b * 7 + (kloc >> 5)) * 8 + (n >> 4)) * 64
          + (n & 15) + ((kloc >> 3) & 3) * 16) * 8 + (kloc & 7);
}

// ---------------------------------------------------------------------------
// K1, 232 blocks x 512 threads (8 waves; per-wave work halved vs round 3):
//   0..199  : msk row + support = feat @ W (MFMA) -> bf16 B-frags in ws
//   200..231: zero-fill K-pad (k=200..223) supp fragment slots
// ---------------------------------------------------------------------------
__global__ __launch_bounds__(512) void prep_kernel(
    const float* __restrict__ feat, const float* __restrict__ weight,
    const float* __restrict__ rew, float* __restrict__ msk,
    short* __restrict__ supp)
{
  const int t = threadIdx.x;
  const int bid = blockIdx.x;

  if (bid >= 200) {                      // ---- K-pad zero-fill ----
    const int b = bid - 200;
    const size_t base = (((size_t)b * 7 + 6) * 8) * 512;  // [b][kc=6][0][0][0]
    for (int q = t; q < 1536; q += 512) {
      const int nt = q / 192, p = q - nt * 192;
      unsigned* dst = (unsigned*)(supp + base + (size_t)nt * 512 + 128) + p;
      *dst = 0u;
    }
    return;
  }

  __shared__ s8v sW[2048];   // W B-frags [kc=4][nt=8][lane=64], 32 KB

  // ---- msk row r = bid: 0.5(R+R^T)+I, zero-padded to 224 cols ----
  {
    const int r = bid;
    if (t < 224) {
      float v = 0.f;
      if (t < 200)
        v = 0.5f * (rew[r * NG + t] + rew[t * NG + r]) + (r == t ? 1.f : 0.f);
      msk[r * 224 + t] = v;
    }
  }

  // ---- stage W fragments: 2048 granules, 4 per thread ----
  for (int p = 0; p < 4; ++p) {
    const int idx = t + p * 512;            // < 2048
    const int n = idx & 127, kg = idx >> 7; // kg 0..15
    s8v v;
#pragma unroll
    for (int e = 0; e < 8; ++e)
      v[e] = f2bf(weight[(kg * 8 + e) * FF + n]);
    sW[((kg >> 2) * 8 + (n >> 4)) * 64 + (n & 15) + (kg & 3) * 16] = v;
  }
  __syncthreads();

  // ---- support rows bid*32 .. +31 via MFMA: wave (mt, nq) ----
  const int w = t >> 6, l = t & 63;
  const int mt = w >> 2, nq = w & 3;        // mt: row-tile, nq: n-quarter (32 cols)
  const int arow = bid * 32 + mt * 16 + (l & 15);
  const int klane = (l >> 4) * 8;

  f4v acc0 = {0.f,0.f,0.f,0.f}, acc1 = acc0;
#pragma unroll
  for (int kc = 0; kc < 4; ++kc) {
    const float* fp = feat + (size_t)arow * FF + kc * 32 + klane;
    const float4 fa = *(const float4*)fp;
    const float4 fb = *(const float4*)(fp + 4);
    s8v af;
    af[0]=f2bf(fa.x); af[1]=f2bf(fa.y); af[2]=f2bf(fa.z); af[3]=f2bf(fa.w);
    af[4]=f2bf(fb.x); af[5]=f2bf(fb.y); af[6]=f2bf(fb.z); af[7]=f2bf(fb.w);
    acc0 = __builtin_amdgcn_mfma_f32_16x16x32_bf16(af, sW[(kc*8 + nq*2 + 0)*64 + l], acc0, 0,0,0);
    acc1 = __builtin_amdgcn_mfma_f32_16x16x32_bf16(af, sW[(kc*8 + nq*2 + 1)*64 + l], acc1, 0,0,0);
  }

  // ---- scatter-store acc as bf16 B-fragments (D: col=l&15, row=(l>>4)*4+reg) ----
#pragma unroll
  for (int reg = 0; reg < 4; ++reg) {
    const int rr = bid * 32 + mt * 16 + (l >> 4) * 4 + reg;
    const unsigned bb = (unsigned)rr / 200u;
    const int kloc = rr - (int)bb * 200;
    const int n0 = nq * 32 + (l & 15);
    supp[supp_elem(bb, kloc, n0)]      = f2bf(acc0[reg]);
    supp[supp_elem(bb, kloc, n0 + 16)] = f2bf(acc1[reg]);
  }
}

// ---------------------------------------------------------------------------
// K2, 256 blocks x 512 threads: out_b = (sigmoid(adj_bb) * msk) @ support_b.
// Wave (mt, nq): per-wave 7 sM reads + 14 supp loads + 14 MFMA (half of r3).
// ---------------------------------------------------------------------------
__global__ __launch_bounds__(512) void graphconv_kernel(
    const float* __restrict__ adj, const float* __restrict__ msk,
    const short* __restrict__ supp, float* __restrict__ out)
{
  __shared__ s8v sM[896];   // M A-frags [mt=2][kc=7][lane=64], swizzled, 14 KB
  const int t = threadIdx.x;
  const int sw2 = (blockIdx.x & 7) * 32 + (blockIdx.x >> 3);  // XCD colocation
  const int b = sw2 >> 3, slab = sw2 & 7;
  const int i0 = slab * 25;

  // ---- Phase A: build M fragments (rows>=200 or cols>=200 -> 0) ----
#pragma unroll
  for (int p = 0; p < 2; ++p) {
    const int idx = t + p * 512;
    if (idx < 896) {                      // 32 rows x 28 j-groups
      const int i = idx / 28, jg = idx - i * 28;
      const int gi = i0 + i;
      s8v v = {0,0,0,0,0,0,0,0};
      if (jg < 25 && gi < 200) {
        const float* ap = adj + ((size_t)(b * NG + gi) * NN + b * NG + jg * 8);
        const float4 a0 = *(const float4*)ap;
        const float4 a1 = *(const float4*)(ap + 4);
        const float* mp = msk + gi * 224 + jg * 8;
        const float4 m0 = *(const float4*)mp;
        const float4 m1 = *(const float4*)(mp + 4);
        v[0] = f2bf(m0.x * sigm(a0.x));
        v[1] = f2bf(m0.y * sigm(a0.y));
        v[2] = f2bf(m0.z * sigm(a0.z));
        v[3] = f2bf(m0.w * sigm(a0.w));
        v[4] = f2bf(m1.x * sigm(a1.x));
        v[5] = f2bf(m1.y * sigm(a1.y));
        v[6] = f2bf(m1.z * sigm(a1.z));
        v[7] = f2bf(m1.w * sigm(a1.w));
      }
      const int g = ((i >> 4) * 7 + (jg >> 2)) * 64 + (i & 15) + (jg & 3) * 16;
      sM[swz(g)] = v;
    }
  }
  __syncthreads();

  // ---- Phase B: 7 K-chunks x 2 N-tiles of MFMA per wave ----
  const int w = t >> 6, l = t & 63;
  const int mt = w >> 2, nq = w & 3;
  const s8v* sb = (const s8v*)supp + (size_t)b * 7 * 8 * 64 + (nq * 2) * 64 + l;

  f4v acc0 = {0.f,0.f,0.f,0.f}, acc1 = acc0;
#pragma unroll
  for (int kc = 0; kc < 7; ++kc) {
    const s8v af = sM[swz((mt * 7 + kc) * 64 + l)];
    acc0 = __builtin_amdgcn_mfma_f32_16x16x32_bf16(af, sb[(kc*8 + 0)*64], acc0, 0,0,0);
    acc1 = __builtin_amdgcn_mfma_f32_16x16x32_bf16(af, sb[(kc*8 + 1)*64], acc1, 0,0,0);
  }

  // ---- store (guard: only first 25 computed rows are real) ----
#pragma unroll
  for (int reg = 0; reg < 4; ++reg) {
    const int rl = mt * 16 + (l >> 4) * 4 + reg;
    if (rl < 25) {
      const size_t o = (size_t)(b * NG + i0 + rl) * FF + nq * 32 + (l & 15);
      out[o]      = acc0[reg];
      out[o + 16] = acc1[reg];
    }
  }
}

// ---------------------------------------------------------------------------
extern "C" void kernel_launch(void* const* d_in, const int* in_sizes, int n_in,
                              void* d_out, int out_size, void* d_ws, size_t ws_size,
                              hipStream_t stream)
{
  const float* adj    = (const float*)d_in[0];  // [6400, 6400]
  const float* feat   = (const float*)d_in[1];  // [6400, 128]
  const float* weight = (const float*)d_in[2];  // [128, 128]
  const float* rew    = (const float*)d_in[3];  // [200, 200]
  float*       out    = (float*)d_out;          // [6400, 128]

  short* supp = (short*)d_ws;                          // 1,835,008 B bf16 frags
  float* msk  = (float*)((char*)d_ws + 1835008);       // [200][224] fp32

  prep_kernel<<<232, 512, 0, stream>>>(feat, weight, rew, msk, supp);
  graphconv_kernel<<<256, 512, 0, stream>>>(adj, msk, supp, out);
}